// Round 9
// baseline (225.851 us; speedup 1.0000x reference)
//
#include <hip/hip_runtime.h>
#include <hip/hip_bf16.h>
#include <math.h>

#define D_MODEL 1024
#define NHEADS  16
#define HDIM    64
#define BATCH   4
#define SEQ     2048

typedef __attribute__((ext_vector_type(8))) short bf16x8;
typedef __attribute__((ext_vector_type(4))) float f32x4;

#if __has_builtin(__builtin_amdgcn_exp2f)
#define EXP2(x) __builtin_amdgcn_exp2f(x)
#else
#define EXP2(x) exp2f(x)
#endif

__device__ __forceinline__ unsigned short f2bf(float f) {
  union { float f; unsigned u; } v; v.f = f;
  unsigned r = v.u + 0x7FFFu + ((v.u >> 16) & 1u);   // RNE
  return (unsigned short)(r >> 16);
}

// pack 2 f32 -> 2 bf16 in one dword (RNE), hw instruction (no builtin, m240)
__device__ __forceinline__ unsigned cvtpk(float lo, float hi) {
  unsigned r;
  asm("v_cvt_pk_bf16_f32 %0, %1, %2" : "=v"(r) : "v"(lo), "v"(hi));
  return r;
}

__device__ __forceinline__ void load_lds16(const unsigned short* g, unsigned short* l) {
  __builtin_amdgcn_global_load_lds(
      (const __attribute__((address_space(1))) unsigned int*)g,
      (__attribute__((address_space(3))) unsigned int*)l, 16, 0, 0);
}

// ---- fused pre-pass: x cast (blocks 0..4095), w_qkv transpose (4096..4863),
//      w_out transpose (4864..5119). ----
__global__ __launch_bounds__(256) void prep_kernel(
    const float* __restrict__ x,     unsigned short* __restrict__ Xb,
    const float* __restrict__ w_qkv, unsigned short* __restrict__ WqT,
    const float* __restrict__ w_out, unsigned short* __restrict__ WoT)
{
  __shared__ float t[64][65];
  const int id  = blockIdx.x;
  const int tid = threadIdx.x;

  if (id < 4096) {                       // ---- cast chunk ----
    const int idx = (id * 256 + tid) * 8;
    float4 a = *(const float4*)&x[idx];
    float4 b = *(const float4*)&x[idx + 4];
    alignas(16) unsigned short o[8] = {
      f2bf(a.x), f2bf(a.y), f2bf(a.z), f2bf(a.w),
      f2bf(b.x), f2bf(b.y), f2bf(b.z), f2bf(b.w)};
    *(uint4*)&Xb[idx] = *(uint4*)o;
    return;
  }

  // ---- transpose_cast: W [1024][N] fp32 -> WT [N][1024] bf16 ----
  const float* W; unsigned short* WT; int N, rblk;
  if (id < 4096 + 768) { W = w_qkv; WT = WqT; N = 3 * D_MODEL; rblk = id - 4096; }
  else                 { W = w_out; WT = WoT; N = D_MODEL;     rblk = id - 4864; }
  const int gx = N / 64;
  const int n0 = (rblk % gx) * 64, k0 = (rblk / gx) * 64;
  const int r = tid >> 2, c0 = (tid & 3) * 16;
  #pragma unroll
  for (int i = 0; i < 16; i += 4) {
    float4 f = *(const float4*)&W[(size_t)(k0 + r) * N + n0 + c0 + i];
    t[r][c0+i] = f.x; t[r][c0+i+1] = f.y; t[r][c0+i+2] = f.z; t[r][c0+i+3] = f.w;
  }
  __syncthreads();
  #pragma unroll
  for (int i = 0; i < 16; i += 4) {
    alignas(8) unsigned short s[4] = {
      f2bf(t[c0+i][r]), f2bf(t[c0+i+1][r]), f2bf(t[c0+i+2][r]), f2bf(t[c0+i+3][r])};
    *(uint2*)&WT[(size_t)(n0 + r) * 1024 + k0 + c0 + i] = *(uint2*)s;
  }
}

// ---- 128x128-tile double-buffered GEMM: 4 waves (2x2), per-wave 64x64.
// LDS 64 KiB -> 2 blocks/CU. Round-9 change: within-XCD block order is
// bm-FAST (8 A-row-panels) then bn-slow, so the ~64 co-resident blocks per
// XCD cover 8bm x 8bn: A-panel (2MB) + B working set (2MB) = 4MB = L2-resident
// (round-8's bn-fast order streamed the 6MB B panel from HBM every row pass:
// FETCH 121MB, 5.5x ideal).
template<int MODE>
__global__ __launch_bounds__(256, 2) void gemm_db(
    const unsigned short* __restrict__ A,
    const unsigned short* __restrict__ Bt,
    const float* __restrict__ bias,
    unsigned short* __restrict__ Qb, unsigned short* __restrict__ Kb,
    unsigned short* __restrict__ Vb, float* __restrict__ Out)
{
  constexpr int N    = (MODE == 0) ? 3 * D_MODEL : D_MODEL;
  constexpr int NT   = D_MODEL / 64;               // 16 K-tiles
  constexpr int GX   = N / 128;                    // 24 or 8
  constexpr int MROW = BATCH * SEQ / 128;          // 64 bm rows
  constexpr int RPX  = MROW / 8;                   // 8 rows per XCD

  // T1 + L2-locality: XCD = id&7 (hw round-robin); within the XCD's chunk,
  // bm_local varies fast (8 rows), bn slow -> resident set L2-fits.
  const int id    = blockIdx.y * GX + blockIdx.x;
  const int xcd   = id & 7;
  const int local = id >> 3;                       // 0 .. GX*RPX-1
  const int bm = (xcd * RPX + (local & (RPX - 1))) * 128;
  const int bn = (local / RPX) * 128;

  const int tid  = threadIdx.x;
  const int lane = tid & 63;
  const int w    = tid >> 6;                       // 0..3
  const int quad = lane >> 4;
  const int l16  = lane & 15;
  const int wr = w >> 1, wc = w & 1;

  // A: [2][128][64] @ 0, B: [2][128][64] @ 16384 (elems); total 64 KiB
  __shared__ __align__(16) unsigned short lds[32768];

  // staging: linear LDS dest, swizzle on per-lane GLOBAL source (rule 21)
  const int srow = lane >> 3;
  const int scol = ((lane & 7) ^ srow) * 8;
  const unsigned short* __restrict__ Ag = A  + (size_t)(bm + w*32 + srow) * D_MODEL + scol;
  const unsigned short* __restrict__ Bg = Bt + (size_t)(bn + w*32 + srow) * D_MODEL + scol;
  const int xs = (l16 & 7) * 8;                    // read-side XOR (elems)

  f32x4 acc[4][4] = {};

  auto stageAll = [&](int buf, int t2) {           // 8 loads/wave (4 A + 4 B)
    unsigned short* dA = &lds[buf*8192 + w*2048];
    unsigned short* dB = &lds[16384 + buf*8192 + w*2048];
    const unsigned short* gA = Ag + t2*64;
    const unsigned short* gB = Bg + t2*64;
    #pragma unroll
    for (int c = 0; c < 4; c++) {
      load_lds16(gA + (size_t)c*8*D_MODEL, dA + c*512);
      load_lds16(gB + (size_t)c*8*D_MODEL, dB + c*512);
    }
  };
  auto rdA = [&](int buf, int mi, int kk) {
    return *(const bf16x8*)&lds[buf*8192 +
        (wr*64 + mi*16 + l16)*64 + (((kk*4 + quad)*8) ^ xs)];
  };
  auto rdB = [&](int buf, int ni, int kk) {
    return *(const bf16x8*)&lds[16384 + buf*8192 +
        (wc*64 + ni*16 + l16)*64 + (((kk*4 + quad)*8) ^ xs)];
  };

  stageAll(0, 0);
  __syncthreads();                                  // tile 0 ready

  for (int t = 0; t < NT; ++t) {
    const int cur = t & 1;
    if (t + 1 < NT) stageAll(cur ^ 1, t + 1);       // issue-early

    #pragma unroll
    for (int kk = 0; kk < 2; kk++) {
      bf16x8 af[4], bfv[4];
      #pragma unroll
      for (int mi = 0; mi < 4; mi++) af[mi]  = rdA(cur, mi, kk);
      #pragma unroll
      for (int ni = 0; ni < 4; ni++) bfv[ni] = rdB(cur, ni, kk);
      __builtin_amdgcn_s_setprio(1);
      #pragma unroll
      for (int mi = 0; mi < 4; mi++)
        #pragma unroll
        for (int ni = 0; ni < 4; ni++)
          acc[mi][ni] = __builtin_amdgcn_mfma_f32_16x16x32_bf16(af[mi], bfv[ni], acc[mi][ni], 0, 0, 0);
      __builtin_amdgcn_s_setprio(0);
    }

    __syncthreads();   // drains staging (issued at tile top) + protects bufs
  }

  // ---- epilogue (per-wave tile = 64x64) ----
  const int b   = bm >> 11;
  const int tl0 = (bm & (SEQ - 1));
  #pragma unroll
  for (int ni = 0; ni < 4; ni++) {
    const int n = bn + wc*64 + ni*16 + l16;
    const float bv = bias[n];
    #pragma unroll
    for (int mi = 0; mi < 4; mi++) {
      const int t0 = tl0 + wr*64 + mi*16 + quad*4;
      if (MODE == 0) {
        const int which = n >> 10;
        const int c = n & 1023;
        const int h = c >> 6, hd = c & 63;
        const size_t bhb = ((size_t)(b*NHEADS + h)) * (SEQ*HDIM);
        if (which == 2) {
          alignas(8) unsigned short pk[4];
          #pragma unroll
          for (int r = 0; r < 4; r++) pk[r] = f2bf(acc[mi][ni][r] + bv);
          *(uint2*)&Vb[bhb + (size_t)hd*SEQ + t0] = *(uint2*)pk;
        } else if (which == 0) {
          #pragma unroll
          for (int r = 0; r < 4; r++)
            Qb[bhb + (size_t)(t0 + r)*HDIM + hd] = f2bf((acc[mi][ni][r] + bv) * 0.18033688f);
        } else {
          #pragma unroll
          for (int r = 0; r < 4; r++)
            Kb[bhb + (size_t)(t0 + r)*HDIM + hd] = f2bf(acc[mi][ni][r] + bv);
        }
      } else {
        const int m = bm + wr*64 + mi*16 + quad*4;
        #pragma unroll
        for (int r = 0; r < 4; r++)
          Out[(size_t)(m + r) * N + n] = acc[mi][ni][r] + bv;
      }
    }
  }
}

// Flash attention v13 (unchanged, round-7/8 passing): one q-tile per block
// (grid 64x16, heavy-first), K/V double-buffer stage-early, one barrier/tile,
// T2 swizzle, T5 setprio, T12-lite softmax (swapped QK^T + cvt_pk + b64).
__global__ __launch_bounds__(256) void attn_kernel(
    const unsigned short* __restrict__ Qb,
    const unsigned short* __restrict__ Kb,
    const unsigned short* __restrict__ Vt,
    unsigned short* __restrict__ Yb)
{
  const int bh   = blockIdx.x;
  const int qt   = 15 - blockIdx.y;            // heavy blocks dispatch first
  const int tid  = threadIdx.x;
  const int wave = tid >> 6;
  const int lane = tid & 63;
  const int quad = lane >> 4;
  const int l16  = lane & 15;

  __shared__ __align__(16) unsigned short Ks[2][64 * 64];   // [buf][key][hd], swz
  __shared__ __align__(16) unsigned short Vs[2][64 * 64];   // [buf][hd][key], swz
  __shared__ __align__(16) unsigned short Pl[8][16][72];    // per-strip P (bf16)

  const unsigned short* __restrict__ qb_ = Qb + (size_t)bh * (SEQ*HDIM);
  const unsigned short* __restrict__ kb_ = Kb + (size_t)bh * (SEQ*HDIM);
  const unsigned short* __restrict__ vb_ = Vt + (size_t)bh * (SEQ*HDIM);
  const int h = bh & (NHEADS - 1);
  const int b = bh >> 4;

  const short ob = (short)0x3F80;    // bf16 1.0
  const bf16x8 ones = {ob,ob,ob,ob,ob,ob,ob,ob};

  const int srow = lane >> 3;                        // 0..7 within 8-row slice
  const int scolswz = ((lane & 7) ^ srow) * 8;       // swizzled 16B slot
  const int krow0 = wave * 16 + srow;                // key-row (K) / hd-row (V) base
  const int xs = (l16 & 7) * 8;                      // read-side XOR (elems)

  auto stage = [&](int buf, int it) {
    const int kb = it * 64;
    #pragma unroll
    for (int j = 0; j < 2; j++)
      load_lds16(kb_ + (size_t)(kb + krow0 + j*8)*HDIM + scolswz,
                 &Ks[buf][wave*1024 + j*512]);
    #pragma unroll
    for (int j = 0; j < 2; j++)
      load_lds16(vb_ + (size_t)(krow0 + j*8)*SEQ + kb + scolswz,
                 &Vs[buf][(wave*16 + j*8)*64]);
  };

  const int nt = 2 * qt + 2;
  const int qs0 = qt * 128 + wave * 32;
  const int myLast = 2 * qt + (wave >> 1);           // last tile this wave needs

  bf16x8 qf[2][2];
  #pragma unroll
  for (int t = 0; t < 2; t++)
    #pragma unroll
    for (int kk = 0; kk < 2; kk++)
      qf[t][kk] = *(const bf16x8*)(qb_ + (qs0 + t*16 + l16)*HDIM + kk*32 + quad*8);

  f32x4 acc[2][4] = {};
  float lrow[2][4] = {};

  stage(0, 0);
  __syncthreads();

  for (int it = 0; it < nt; it++) {
    const int cur = it & 1;

    if (it + 1 < nt) stage(cur ^ 1, it + 1);

    if (it <= myLast) {
      const int kb = it * 64;
      // S^T: swapped operands -> sfr[nf][r] = S[key=kb+nf*16+quad*4+r][q=qs0+strip*16+l16]
      f32x4 sfr[4] = {}, sfr1[4] = {};
      __builtin_amdgcn_s_setprio(1);
      #pragma unroll
      for (int kk = 0; kk < 2; kk++)
        #pragma unroll
        for (int nf = 0; nf < 4; nf++) {
          const bf16x8 kf = *(const bf16x8*)&Ks[cur][(nf*16 + l16)*64 + ((kk*32 + quad*8) ^ xs)];
          sfr[nf]  = __builtin_amdgcn_mfma_f32_16x16x32_bf16(kf, qf[0][kk], sfr[nf], 0, 0, 0);
          sfr1[nf] = __builtin_amdgcn_mfma_f32_16x16x32_bf16(kf, qf[1][kk], sfr1[nf], 0, 0, 0);
        }
      __builtin_amdgcn_s_setprio(0);

      if (it == myLast) {
        #pragma unroll
        for (int nf = 0; nf < 4; nf++) {
          const int key = kb + nf*16 + quad*4;
          #pragma unroll
          for (int r = 0; r < 4; r++) {
            sfr[nf][r]  = (key + r > qs0 + l16)      ? -INFINITY : sfr[nf][r];
            sfr1[nf][r] = (key + r > qs0 + 16 + l16) ? -INFINITY : sfr1[nf][r];
          }
        }
      }

      // P = exp2(S), hw pack, b64 write: Pl[strip][q=l16][k=nf*16+quad*4..+3]
      #pragma unroll
      for (int nf = 0; nf < 4; nf++) {
        uint2 p0, p1;
        p0.x = cvtpk(EXP2(sfr[nf][0]),  EXP2(sfr[nf][1]));
        p0.y = cvtpk(EXP2(sfr[nf][2]),  EXP2(sfr[nf][3]));
        p1.x = cvtpk(EXP2(sfr1[nf][0]), EXP2(sfr1[nf][1]));
        p1.y = cvtpk(EXP2(sfr1[nf][2]), EXP2(sfr1[nf][3]));
        *(uint2*)&Pl[wave*2 + 0][l16][nf*16 + quad*4] = p0;
        *(uint2*)&Pl[wave*2 + 1][l16][nf*16 + quad*4] = p1;
      }

      // PV for both strips — v11-verbatim (per-strip V-frag reads)
      #pragma unroll
      for (int t = 0; t < 2; t++) {
        f32x4 rsum = {};
        __builtin_amdgcn_s_setprio(1);
        #pragma unroll
        for (int kk = 0; kk < 2; kk++) {
          const bf16x8 pf = *(const bf16x8*)&Pl[wave*2 + t][l16][kk*32 + quad*8];
          #pragma unroll
          for (int nf = 0; nf < 4; nf++) {
            const bf16x8 vf = *(const bf16x8*)&Vs[cur][(nf*16 + l16)*64 + ((kk*32 + quad*8) ^ xs)];
            acc[t][nf] = __builtin_amdgcn_mfma_f32_16x16x32_bf16(pf, vf, acc[t][nf], 0, 0, 0);
          }
          rsum = __builtin_amdgcn_mfma_f32_16x16x32_bf16(pf, ones, rsum, 0, 0, 0);
        }
        __builtin_amdgcn_s_setprio(0);
        #pragma unroll
        for (int r = 0; r < 4; r++) lrow[t][r] += rsum[r];
      }
    }

    __syncthreads();   // drains staging (issued a full tile earlier) + protects bufs
  }

  // O /= l, write y (B,T,C) bf16
  #pragma unroll
  for (int t = 0; t < 2; t++) {
    #pragma unroll
    for (int r = 0; r < 4; r++) {
      const float inv = 1.0f / lrow[t][r];
      const int trow = qs0 + t*16 + quad*4 + r;
      const size_t off = ((size_t)(b * SEQ + trow)) * D_MODEL + h * HDIM;
      #pragma unroll
      for (int nf = 0; nf < 4; nf++)
        Yb[off + nf*16 + l16] = f2bf(acc[t][nf][r] * inv);
    }
  }
}

extern "C" void kernel_launch(void* const* d_in, const int* in_sizes, int n_in,
                              void* d_out, int out_size, void* d_ws, size_t ws_size,
                              hipStream_t stream) {
  const float* x     = (const float*)d_in[0];
  const float* w_qkv = (const float*)d_in[1];
  const float* b_qkv = (const float*)d_in[2];
  const float* w_out = (const float*)d_in[3];
  const float* b_out = (const float*)d_in[4];
  float* out = (float*)d_out;

  const size_t SZ = (size_t)BATCH * NHEADS * SEQ * HDIM;   // 8M elems
  unsigned short* Qb  = (unsigned short*)d_ws;             // 16 MiB
  unsigned short* Kb  = Qb + SZ;                           // 16 MiB
  unsigned short* Vb  = Kb + SZ;                           // 16 MiB (V^T)
  unsigned short* Xb  = Vb + SZ;                           // 16 MiB, aliased by Yb
  unsigned short* Yb  = Xb;                                // attn writes after gemm0 reads
  unsigned short* WqT = Xb + SZ;                           // 6 MiB
  unsigned short* WoT = WqT + (size_t)3*D_MODEL*D_MODEL;   // 2 MiB

  prep_kernel<<<dim3(4096 + 768 + 256), 256, 0, stream>>>(
      x, Xb, w_qkv, WqT, w_out, WoT);

  gemm_db<0><<<dim3(3*D_MODEL/128, BATCH*SEQ/128), 256, 0, stream>>>(
      Xb, WqT, b_qkv, Qb, Kb, Vb, nullptr);
  attn_kernel<<<dim3(BATCH*NHEADS, 16), 256, 0, stream>>>(Qb, Kb, Vb, Yb);
  gemm_db<1><<<dim3(D_MODEL/128, BATCH*SEQ/128), 256, 0, stream>>>(
      Yb, WoT, b_out, nullptr, nullptr, nullptr, out);
}